// Round 1
// baseline (966.502 us; speedup 1.0000x reference)
//
#include <hip/hip_runtime.h>

#define FDIM 32

// ---- degree count: deg[c] += 1 for each edge target ----
__global__ void k_deg(const int* __restrict__ col, float* __restrict__ deg, int E) {
    int i = blockIdx.x * blockDim.x + threadIdx.x;
    if (i < E) atomicAdd(&deg[col[i]], 1.0f);
}

// ---- layer 1: dinv = rsqrt(deg+1); g = dinv * (x @ W1); acc = g (self-loop) ----
__global__ void k_l1(const float* __restrict__ x, const float* __restrict__ W1,
                     const float* __restrict__ deg, float* __restrict__ dinv,
                     float* __restrict__ g, float* __restrict__ acc, int N) {
    int idx = blockIdx.x * blockDim.x + threadIdx.x;
    int i = idx >> 5, f = idx & 31;
    if (i >= N) return;
    float dv = rsqrtf(deg[i] + 1.0f);
    if (f == 0) dinv[i] = dv;
    float v = fmaf(x[2 * i], W1[f], x[2 * i + 1] * W1[FDIM + f]);
    float gg = dv * v;
    g[idx]   = gg;   // idx == i*32 + f
    acc[idx] = gg;
}

// ---- edge scatter: acc[col] += g[row], thread per (edge, feature) ----
__global__ void k_scatter(const int* __restrict__ row, const int* __restrict__ col,
                          const float* __restrict__ g, float* acc, int total) {
    int idx = blockIdx.x * blockDim.x + threadIdx.x;
    if (idx >= total) return;
    int e = idx >> 5, f = idx & 31;
    atomicAdd(&acc[col[e] * FDIM + f], g[row[e] * FDIM + f]);
}

// ---- layer 2: h1 = relu(dinv*acc1 + b1); g2 = dinv * (h1 @ W2); acc2 = g2 ----
// acc2 may alias acc1: reads complete before __syncthreads, writes after,
// and each block touches only its own 8 rows.
__global__ void k_l2(const float* __restrict__ dinv, const float* acc1,
                     const float* __restrict__ b1, const float* __restrict__ W2,
                     float* __restrict__ g2, float* acc2, int N) {
    __shared__ float sW[FDIM * FDIM];
    __shared__ float sh[8][FDIM];
    int t = threadIdx.x;
    for (int k = t; k < FDIM * FDIM; k += 256) sW[k] = W2[k];
    int i = blockIdx.x * 8 + (t >> 5), f = t & 31;
    float o = 0.0f, dv = 0.0f;
    if (i < N) {
        dv = dinv[i];
        o = fmaxf(fmaf(dv, acc1[i * FDIM + f], b1[f]), 0.0f);
    }
    sh[t >> 5][f] = o;
    __syncthreads();
    if (i < N) {
        float s = 0.0f;
        #pragma unroll
        for (int k = 0; k < FDIM; ++k) s = fmaf(sh[t >> 5][k], sW[k * FDIM + f], s);
        float gg = dv * s;
        g2[i * FDIM + f]  = gg;
        acc2[i * FDIM + f] = gg;
    }
}

// ---- finalize layer 2 + pool scatter ----
__global__ void k_pool(const float* __restrict__ dinv, const float* __restrict__ acc,
                       const float* __restrict__ b2, const int* __restrict__ batch,
                       float* __restrict__ pool, float* __restrict__ cnt, int N) {
    int idx = blockIdx.x * blockDim.x + threadIdx.x;
    int i = idx >> 5, f = idx & 31;
    if (i >= N) return;
    float h = fmaf(dinv[i], acc[idx], b2[f]);
    int b = batch[i];
    atomicAdd(&pool[b * FDIM + f], h);
    if (f == 0) atomicAdd(&cnt[b], 1.0f);
}

// ---- mean ----
__global__ void k_out(const float* __restrict__ pool, const float* __restrict__ cnt,
                      float* __restrict__ out, int total) {
    int idx = blockIdx.x * blockDim.x + threadIdx.x;
    if (idx >= total) return;
    out[idx] = pool[idx] / fmaxf(cnt[idx >> 5], 1.0f);
}

extern "C" void kernel_launch(void* const* d_in, const int* in_sizes, int n_in,
                              void* d_out, int out_size, void* d_ws, size_t ws_size,
                              hipStream_t stream) {
    const float* x   = (const float*)d_in[0];
    const int*   ei  = (const int*)d_in[1];
    const int* batch = (const int*)d_in[2];
    const float* W1  = (const float*)d_in[4];
    const float* b1  = (const float*)d_in[5];
    const float* W2  = (const float*)d_in[6];
    const float* b2  = (const float*)d_in[7];
    float* out = (float*)d_out;

    int N = in_sizes[0] / 2;   // x is [N, 2]
    int E = in_sizes[1] / 2;   // edge_index is [2, E]
    int G = out_size / FDIM;

    const int* row = ei;       // edge_index[0] : source
    const int* col = ei + E;   // edge_index[1] : target (aggregation)

    float* ws   = (float*)d_ws;
    float* deg  = ws;                         // N
    float* dinv = deg + N;                    // N
    float* bufG = dinv + N;                   // N*32  (g of current layer)
    float* bufA = bufG + (size_t)N * FDIM;    // N*32  (accumulator)
    float* pool = bufA + (size_t)N * FDIM;    // G*32
    float* cnt  = pool + (size_t)G * FDIM;    // G

    hipMemsetAsync(deg, 0, (size_t)N * sizeof(float), stream);
    hipMemsetAsync(pool, 0, (size_t)(G * FDIM + G) * sizeof(float), stream);

    k_deg<<<(E + 255) / 256, 256, 0, stream>>>(col, deg, E);

    int nt = N * FDIM;
    k_l1<<<(nt + 255) / 256, 256, 0, stream>>>(x, W1, deg, dinv, bufG, bufA, N);

    int ts = E * FDIM;  // 102.4M, fits int
    k_scatter<<<(ts + 255) / 256, 256, 0, stream>>>(row, col, bufG, bufA, ts);

    k_l2<<<(N + 7) / 8, 256, 0, stream>>>(dinv, bufA, b1, W2, bufG, bufA, N);

    k_scatter<<<(ts + 255) / 256, 256, 0, stream>>>(row, col, bufG, bufA, ts);

    k_pool<<<(nt + 255) / 256, 256, 0, stream>>>(dinv, bufA, b2, batch, pool, cnt, N);
    k_out<<<(out_size + 255) / 256, 256, 0, stream>>>(pool, cnt, out, out_size);
}

// Round 2
// 661.651 us; speedup vs baseline: 1.4607x; 1.4607x over previous
//
#include <hip/hip_runtime.h>

#define FDIM 32

// ---------- shared: histogram of col (in-degree counts, excl self-loop) ----------
__global__ void k_hist(const int* __restrict__ col, unsigned int* __restrict__ count, int E) {
    int i = blockIdx.x * blockDim.x + threadIdx.x;
    if (i < E) atomicAdd(&count[col[i]], 1u);
}

// ---------- scan step 1: per-block (256) sums ----------
__global__ void k_scan1(const unsigned int* __restrict__ count, unsigned int* __restrict__ bsum, int N) {
    __shared__ unsigned int s[256];
    int i = blockIdx.x * 256 + threadIdx.x;
    s[threadIdx.x] = (i < N) ? count[i] : 0u;
    __syncthreads();
    for (int off = 128; off > 0; off >>= 1) {
        if (threadIdx.x < off) s[threadIdx.x] += s[threadIdx.x + off];
        __syncthreads();
    }
    if (threadIdx.x == 0) bsum[blockIdx.x] = s[0];
}

// ---------- scan step 2: exclusive scan of block sums (1 block, chunked, any NB) ----------
__global__ void k_scan2(unsigned int* bsum, int NB) {
    __shared__ unsigned int s[256];
    __shared__ unsigned int carry;
    int t = threadIdx.x;
    if (t == 0) carry = 0u;
    __syncthreads();
    for (int base = 0; base < NB; base += 256) {
        int i = base + t;
        unsigned int v = (i < NB) ? bsum[i] : 0u;
        s[t] = v;
        __syncthreads();
        for (int off = 1; off < 256; off <<= 1) {
            unsigned int u = (t >= off) ? s[t - off] : 0u;
            __syncthreads();
            s[t] += u;
            __syncthreads();
        }
        unsigned int c = carry;
        if (i < NB) bsum[i] = c + s[t] - v;   // exclusive
        __syncthreads();
        if (t == 255) carry = c + s[255];
        __syncthreads();
    }
}

// ---------- scan step 3: in-block exclusive scan + block offset -> row_ptr, cursor ----------
__global__ void k_scan3(const unsigned int* __restrict__ count, const unsigned int* __restrict__ bsum,
                        int* __restrict__ row_ptr, int* __restrict__ cursor, int N) {
    __shared__ unsigned int s[256];
    int t = threadIdx.x;
    int i = blockIdx.x * 256 + t;
    unsigned int v = (i < N) ? count[i] : 0u;
    s[t] = v;
    __syncthreads();
    for (int off = 1; off < 256; off <<= 1) {
        unsigned int u = (t >= off) ? s[t - off] : 0u;
        __syncthreads();
        s[t] += u;
        __syncthreads();
    }
    if (i < N) {
        int start = (int)(bsum[blockIdx.x] + s[t] - v);
        row_ptr[i] = start;
        cursor[i]  = start;
    }
}

// ---------- counting-sort permute: sorted_row[segment(col)] = row ----------
__global__ void k_permute(const int* __restrict__ row, const int* __restrict__ col,
                          int* cursor, int* __restrict__ sorted_row, int E) {
    int e = blockIdx.x * blockDim.x + threadIdx.x;
    if (e < E) {
        int c = col[e];
        int pos = atomicAdd(&cursor[c], 1);
        sorted_row[pos] = row[e];
    }
}

// ---------- layer 1: dinv = rsqrt(count+1); g = dinv * (x @ W1); optional acc init ----------
__global__ void k_l1(const float* __restrict__ x, const float* __restrict__ W1,
                     const unsigned int* __restrict__ count, float* __restrict__ dinv,
                     float* __restrict__ g, float* acc, int N) {
    int idx = blockIdx.x * blockDim.x + threadIdx.x;
    int i = idx >> 5, f = idx & 31;
    if (i >= N) return;
    float dv = rsqrtf((float)count[i] + 1.0f);
    if (f == 0) dinv[i] = dv;
    float v = fmaf(x[2 * i], W1[f], x[2 * i + 1] * W1[FDIM + f]);
    float gg = dv * v;
    g[idx] = gg;
    if (acc) acc[idx] = gg;
}

// ---------- CSR gather segment-sum: out[i] = g[i] + sum_j g[sorted_row[j]] ----------
__global__ void k_agg(const int* __restrict__ row_ptr, const unsigned int* __restrict__ count,
                      const int* __restrict__ sorted_row, const float* __restrict__ g,
                      float* __restrict__ out, int N) {
    int t = threadIdx.x;
    int i = blockIdx.x * 8 + (t >> 5), f = t & 31;
    if (i >= N) return;
    int s = row_ptr[i];
    int e = s + (int)count[i];
    float acc = g[i * FDIM + f];   // self loop
    int j = s;
    for (; j + 4 <= e; j += 4) {
        int r0 = sorted_row[j], r1 = sorted_row[j + 1], r2 = sorted_row[j + 2], r3 = sorted_row[j + 3];
        float a0 = g[r0 * FDIM + f], a1 = g[r1 * FDIM + f];
        float a2 = g[r2 * FDIM + f], a3 = g[r3 * FDIM + f];
        acc += a0; acc += a1; acc += a2; acc += a3;
    }
    for (; j < e; ++j) acc += g[sorted_row[j] * FDIM + f];
    out[i * FDIM + f] = acc;
}

// ---------- fallback atomic scatter (old path) ----------
__global__ void k_scatter(const int* __restrict__ row, const int* __restrict__ col,
                          const float* __restrict__ g, float* acc, int total) {
    int idx = blockIdx.x * blockDim.x + threadIdx.x;
    if (idx >= total) return;
    int e = idx >> 5, f = idx & 31;
    atomicAdd(&acc[col[e] * FDIM + f], g[row[e] * FDIM + f]);
}

// ---------- layer 2: h1 = relu(dinv*agg1 + b1); g2 = dinv * (h1 @ W2); optional acc init ----------
__global__ void k_l2(const float* __restrict__ dinv, const float* agg1,
                     const float* __restrict__ b1, const float* __restrict__ W2,
                     float* __restrict__ g2, float* acc2, int N) {
    __shared__ float sW[FDIM * FDIM];
    __shared__ float sh[8][FDIM];
    int t = threadIdx.x;
    for (int k = t; k < FDIM * FDIM; k += 256) sW[k] = W2[k];
    int i = blockIdx.x * 8 + (t >> 5), f = t & 31;
    float o = 0.0f, dv = 0.0f;
    if (i < N) {
        dv = dinv[i];
        o = fmaxf(fmaf(dv, agg1[i * FDIM + f], b1[f]), 0.0f);
    }
    sh[t >> 5][f] = o;
    __syncthreads();
    if (i < N) {
        float s = 0.0f;
        #pragma unroll
        for (int k = 0; k < FDIM; ++k) s = fmaf(sh[t >> 5][k], sW[k * FDIM + f], s);
        float gg = dv * s;
        g2[i * FDIM + f] = gg;
        if (acc2) acc2[i * FDIM + f] = gg;
    }
}

// ---------- finalize layer 2 + pool scatter ----------
__global__ void k_pool(const float* __restrict__ dinv, const float* __restrict__ acc,
                       const float* __restrict__ b2, const int* __restrict__ batch,
                       float* __restrict__ pool, float* __restrict__ cnt, int N) {
    int idx = blockIdx.x * blockDim.x + threadIdx.x;
    int i = idx >> 5, f = idx & 31;
    if (i >= N) return;
    float h = fmaf(dinv[i], acc[idx], b2[f]);
    int b = batch[i];
    atomicAdd(&pool[b * FDIM + f], h);
    if (f == 0) atomicAdd(&cnt[b], 1.0f);
}

// ---------- mean ----------
__global__ void k_out(const float* __restrict__ pool, const float* __restrict__ cnt,
                      float* __restrict__ out, int total) {
    int idx = blockIdx.x * blockDim.x + threadIdx.x;
    if (idx >= total) return;
    out[idx] = pool[idx] / fmaxf(cnt[idx >> 5], 1.0f);
}

extern "C" void kernel_launch(void* const* d_in, const int* in_sizes, int n_in,
                              void* d_out, int out_size, void* d_ws, size_t ws_size,
                              hipStream_t stream) {
    const float* x   = (const float*)d_in[0];
    const int*   ei  = (const int*)d_in[1];
    const int* batch = (const int*)d_in[2];
    const float* W1  = (const float*)d_in[4];
    const float* b1  = (const float*)d_in[5];
    const float* W2  = (const float*)d_in[6];
    const float* b2  = (const float*)d_in[7];
    float* out = (float*)d_out;

    int N = in_sizes[0] / 2;   // x is [N, 2]
    int E = in_sizes[1] / 2;   // edge_index is [2, E]
    int G = out_size / FDIM;

    const int* row = ei;       // edge_index[0] : source
    const int* col = ei + E;   // edge_index[1] : target (aggregation)

    int nt = N * FDIM;
    int NB = (N + 255) / 256;

    // CSR-path workspace need (elements):
    // count N + row_ptr N + cursor N + bsum 1024 + sorted E + dinv N + bufG 32N + bufA 32N + pool 32G + cnt G
    size_t elemsCSR = 68ull * (size_t)N + (size_t)E + 1024 + 33ull * (size_t)G;

    if (ws_size >= elemsCSR * 4) {
        unsigned int* count  = (unsigned int*)d_ws;          // N
        int* row_ptr         = (int*)(count + N);            // N
        int* cursor          = row_ptr + N;                  // N
        unsigned int* bsum   = (unsigned int*)(cursor + N);  // 1024
        int* sorted_row      = (int*)(bsum + 1024);          // E
        float* dinv          = (float*)(sorted_row + E);     // N
        float* bufG          = dinv + N;                     // N*32
        float* bufA          = bufG + (size_t)N * FDIM;      // N*32
        float* pool          = bufA + (size_t)N * FDIM;      // G*32
        float* cnt           = pool + (size_t)G * FDIM;      // G

        hipMemsetAsync(count, 0, (size_t)N * 4, stream);
        hipMemsetAsync(pool, 0, (size_t)(G * FDIM + G) * 4, stream);

        k_hist<<<(E + 255) / 256, 256, 0, stream>>>(col, count, E);
        k_scan1<<<NB, 256, 0, stream>>>(count, bsum, N);
        k_scan2<<<1, 256, 0, stream>>>(bsum, NB);
        k_scan3<<<NB, 256, 0, stream>>>(count, bsum, row_ptr, cursor, N);
        k_permute<<<(E + 255) / 256, 256, 0, stream>>>(row, col, cursor, sorted_row, E);

        k_l1<<<(nt + 255) / 256, 256, 0, stream>>>(x, W1, count, dinv, bufG, nullptr, N);
        k_agg<<<(N + 7) / 8, 256, 0, stream>>>(row_ptr, count, sorted_row, bufG, bufA, N);
        k_l2<<<(N + 7) / 8, 256, 0, stream>>>(dinv, bufA, b1, W2, bufG, nullptr, N);
        k_agg<<<(N + 7) / 8, 256, 0, stream>>>(row_ptr, count, sorted_row, bufG, bufA, N);
        k_pool<<<(nt + 255) / 256, 256, 0, stream>>>(dinv, bufA, b2, batch, pool, cnt, N);
        k_out<<<(out_size + 255) / 256, 256, 0, stream>>>(pool, cnt, out, out_size);
    } else {
        // fallback: proven atomic-scatter path (R0)
        unsigned int* count = (unsigned int*)d_ws;           // N
        float* dinv         = (float*)(count + N);           // N
        float* bufG         = dinv + N;                      // N*32
        float* bufA         = bufG + (size_t)N * FDIM;       // N*32
        float* pool         = bufA + (size_t)N * FDIM;       // G*32
        float* cnt          = pool + (size_t)G * FDIM;       // G

        hipMemsetAsync(count, 0, (size_t)N * 4, stream);
        hipMemsetAsync(pool, 0, (size_t)(G * FDIM + G) * 4, stream);

        k_hist<<<(E + 255) / 256, 256, 0, stream>>>(col, count, E);
        k_l1<<<(nt + 255) / 256, 256, 0, stream>>>(x, W1, count, dinv, bufG, bufA, N);
        int ts = E * FDIM;
        k_scatter<<<(ts + 255) / 256, 256, 0, stream>>>(row, col, bufG, bufA, ts);
        k_l2<<<(N + 7) / 8, 256, 0, stream>>>(dinv, bufA, b1, W2, bufG, bufA, N);
        k_scatter<<<(ts + 255) / 256, 256, 0, stream>>>(row, col, bufG, bufA, ts);
        k_pool<<<(nt + 255) / 256, 256, 0, stream>>>(dinv, bufA, b2, batch, pool, cnt, N);
        k_out<<<(out_size + 255) / 256, 256, 0, stream>>>(pool, cnt, out, out_size);
    }
}